// Round 6
// baseline (1236.202 us; speedup 1.0000x reference)
//
#include <hip/hip_runtime.h>
#include <math.h>

#define HGRID   512
#define NCODES  1024
#define FDIM    8
#define NPTS    65536
#define NCELLS  (HGRID * HGRID)

typedef float f32x4 __attribute__((ext_vector_type(4)));

// ---------------------------------------------------------------------------
// Phase 0: zero the touched-cell bitmap (ws is poisoned 0xAA each launch).
// ---------------------------------------------------------------------------
__global__ void vqrf_init_bitmap(uint32_t* __restrict__ bm) {
    int i = blockIdx.x * blockDim.x + threadIdx.x;
    if (i < NCELLS / 32) bm[i] = 0u;
}

// ---------------------------------------------------------------------------
// Phase 1: mark the 4 corner cells of each point. 262144 atomicOr over 8192
// words — L2-resident, trivial cost.
// ---------------------------------------------------------------------------
__global__ void vqrf_mark_cells(const float* __restrict__ coords,
                                uint32_t* __restrict__ bm) {
    int p = blockIdx.x * blockDim.x + threadIdx.x;
    if (p >= NPTS) return;
    float2 c = ((const float2*)coords)[p];
    float fx = c.x * (float)HGRID;
    float fy = c.y * (float)HGRID;
    int xi = (int)floorf(fx), yi = (int)floorf(fy);
    xi = min(max(xi, 0), HGRID - 1);
    yi = min(max(yi, 0), HGRID - 1);
    int xi1 = min(xi + 1, HGRID - 1);
    int yi1 = min(yi + 1, HGRID - 1);
    int c0 = xi  * HGRID + yi,  c1 = xi  * HGRID + yi1;
    int c2 = xi1 * HGRID + yi,  c3 = xi1 * HGRID + yi1;
    atomicOr(&bm[c0 >> 5], 1u << (c0 & 31));
    atomicOr(&bm[c1 >> 5], 1u << (c1 & 31));
    atomicOr(&bm[c2 >> 5], 1u << (c2 & 31));
    atomicOr(&bm[c3 >> 5], 1u << (c3 & 31));
}

// ---------------------------------------------------------------------------
// Phase 2: one wave per touched cell — argmax over its 1024 codes.
// Lane i reads 16B at [lane + k*64] => 64 lanes * 16 B = 1 KiB per
// instruction, perfectly coalesced; 4 iterations cover the 4 KiB row.
// Non-temporal: this stream is read exactly once.
// First-index tie-break (strictly-greater intra-lane + min-index-on-equal in
// the butterfly) matches jnp.argmax semantics.
// ---------------------------------------------------------------------------
__global__ void __launch_bounds__(256)
vqrf_argmax_cells(const float* __restrict__ hm,
                  const uint32_t* __restrict__ bm,
                  int* __restrict__ idx_map) {
    int cell = blockIdx.x * 4 + (threadIdx.x >> 6);
    int lane = threadIdx.x & 63;
    if (!((bm[cell >> 5] >> (cell & 31)) & 1u)) return;   // wave-uniform skip

    const f32x4* row = (const f32x4*)(hm + (size_t)cell * NCODES);
    float bv = -INFINITY;
    int   bi = 0;
#pragma unroll
    for (int k = 0; k < 4; ++k) {
        f32x4 v = __builtin_nontemporal_load(&row[lane + k * 64]);
        int base = (lane + k * 64) * 4;
        if (v.x > bv) { bv = v.x; bi = base;     }
        if (v.y > bv) { bv = v.y; bi = base + 1; }
        if (v.z > bv) { bv = v.z; bi = base + 2; }
        if (v.w > bv) { bv = v.w; bi = base + 3; }
    }
#pragma unroll
    for (int off = 32; off; off >>= 1) {
        float ov = __shfl_xor(bv, off);
        int   oi = __shfl_xor(bi, off);
        if (ov > bv || (ov == bv && oi < bi)) { bv = ov; bi = oi; }
    }
    if (lane == 0) idx_map[cell] = bi;
}

// ---------------------------------------------------------------------------
// Phase 3: per-point bilinear gather + MLP. idx_map (1 MiB) and
// hash_features (32 KiB) are L2-hot; W1/W2 staged in LDS (uniform-index
// reads broadcast, no bank conflicts).
// ---------------------------------------------------------------------------
__global__ void __launch_bounds__(256)
vqrf_eval_points(const float* __restrict__ coords,
                 const int* __restrict__ idx_map,
                 const float* __restrict__ hf,
                 const float* __restrict__ W1,
                 const float* __restrict__ W2,
                 float* __restrict__ out) {
    __shared__ float sW1[FDIM * 32];
    __shared__ float sW2[32 * 3];
    int tid = threadIdx.x;
    if (tid < FDIM * 32) sW1[tid] = W1[tid];
    if (tid < 96)        sW2[tid] = W2[tid];
    __syncthreads();

    int p = blockIdx.x * blockDim.x + tid;
    if (p >= NPTS) return;

    float2 c2v = ((const float2*)coords)[p];
    float fx = c2v.x * (float)HGRID;
    float fy = c2v.y * (float)HGRID;
    float x0 = floorf(fx), y0 = floorf(fy);
    float wx = fx - x0,    wy = fy - y0;
    int xi = (int)x0, yi = (int)y0;
    xi = min(max(xi, 0), HGRID - 1);
    yi = min(max(yi, 0), HGRID - 1);
    int xi1 = min(xi + 1, HGRID - 1);
    int yi1 = min(yi + 1, HGRID - 1);

    int   cells[4] = { xi  * HGRID + yi, xi  * HGRID + yi1,
                       xi1 * HGRID + yi, xi1 * HGRID + yi1 };
    float wts[4]   = { (1.f - wx) * (1.f - wy), (1.f - wx) * wy,
                       wx * (1.f - wy),         wx * wy };

    float f[FDIM] = {0, 0, 0, 0, 0, 0, 0, 0};
#pragma unroll
    for (int c = 0; c < 4; ++c) {
        int ci = idx_map[cells[c]];
        const float4* fp = (const float4*)(hf + (size_t)ci * FDIM);
        float4 a = fp[0], b = fp[1];
        float w = wts[c];
        f[0] += w * a.x; f[1] += w * a.y; f[2] += w * a.z; f[3] += w * a.w;
        f[4] += w * b.x; f[5] += w * b.y; f[6] += w * b.z; f[7] += w * b.w;
    }

    float o0 = 0.f, o1 = 0.f, o2 = 0.f;
#pragma unroll
    for (int j = 0; j < 32; ++j) {
        float h = 0.f;
#pragma unroll
        for (int k = 0; k < FDIM; ++k) h += f[k] * sW1[k * 32 + j];
        h = fmaxf(h, 0.f);
        o0 += h * sW2[j * 3 + 0];
        o1 += h * sW2[j * 3 + 1];
        o2 += h * sW2[j * 3 + 2];
    }
    out[3 * p + 0] = 1.f / (1.f + expf(-o0));
    out[3 * p + 1] = 1.f / (1.f + expf(-o1));
    out[3 * p + 2] = 1.f / (1.f + expf(-o2));
}

// ---------------------------------------------------------------------------
extern "C" void kernel_launch(void* const* d_in, const int* in_sizes, int n_in,
                              void* d_out, int out_size, void* d_ws, size_t ws_size,
                              hipStream_t stream) {
    const float* coords  = (const float*)d_in[0];
    const float* hashmap = (const float*)d_in[1];
    const float* hf      = (const float*)d_in[2];
    const float* W1      = (const float*)d_in[3];
    const float* W2      = (const float*)d_in[4];
    float* out = (float*)d_out;

    uint32_t* bm      = (uint32_t*)d_ws;                       // 32 KiB
    int*      idx_map = (int*)((char*)d_ws + NCELLS / 8);      // 1 MiB

    hipLaunchKernelGGL(vqrf_init_bitmap, dim3((NCELLS / 32 + 255) / 256), dim3(256),
                       0, stream, bm);
    hipLaunchKernelGGL(vqrf_mark_cells, dim3(NPTS / 256), dim3(256),
                       0, stream, coords, bm);
    hipLaunchKernelGGL(vqrf_argmax_cells, dim3(NCELLS / 4), dim3(256),
                       0, stream, hashmap, bm, idx_map);
    hipLaunchKernelGGL(vqrf_eval_points, dim3(NPTS / 256), dim3(256),
                       0, stream, coords, idx_map, hf, W1, W2, out);
}